// Round 1
// baseline (458.499 us; speedup 1.0000x reference)
//
#include <hip/hip_runtime.h>
#include <math.h>

#define N_ROWS 128
#define HID 64
#define HW 524288            // 1024*512
#define HW4 131072           // HW/4 = 2^17
#define ETA_STRIDE 8         // floats per row in the eta table

// ---------------------------------------------------------------------------
// Kernel 1: compute eta[n] = [e0,e1,e2,e3] and slope=(e1-e0)/(e3-e2) per row.
// One block, 128 threads, one thread per row n. Tiny MLP 4->64->4.
// ---------------------------------------------------------------------------
__global__ __launch_bounds__(N_ROWS) void eta_kernel(
    const float* __restrict__ rt_, const float* __restrict__ noise,
    const float* __restrict__ X_min, const float* __restrict__ X_max,
    const float* __restrict__ Y_min, const float* __restrict__ Y_max,
    const float* __restrict__ W1, const float* __restrict__ b1,
    const float* __restrict__ W2, const float* __restrict__ b2,
    float* __restrict__ eta_ws) {
  const int n = threadIdx.x;  // row 0..127

  // rt_temp = sigmoid(rt_) ; RTn = [rt0, rt1, rt2, 0]
  const float rt0 = 1.0f / (1.0f + expf(-rt_[0]));
  const float rt1 = 1.0f / (1.0f + expf(-rt_[1]));
  const float rt2 = 1.0f / (1.0f + expf(-rt_[2]));

  const float xm0 = X_min[0], xm1 = X_min[1], xm2 = X_min[2], xm3 = X_min[3];
  const float xr0 = X_max[0] - xm0, xr1 = X_max[1] - xm1;
  const float xr2 = X_max[2] - xm2, xr3 = X_max[3] - xm3;

  const float RT0 = rt0 * xr0 + xm0;
  const float RT1 = rt1 * xr1 + xm1;
  const float RT2 = rt2 * xr2 + xm2;

  const float no0 = noise[n * 4 + 0];
  const float no1 = noise[n * 4 + 1];
  const float no2 = noise[n * 4 + 2];

  const float ext0 = RT0 * no0;
  const float ext1 = RT1 * no1;
  const float ext2 = RT2 * no2;
  const float ext3 = ext1 / ext2;   // RT_noisy1 / RT_noisy2

  const float xn0 = (ext0 - xm0) / xr0;
  const float xn1 = (ext1 - xm1) / xr1;
  const float xn2 = (ext2 - xm2) / xr2;
  const float xn3 = (ext3 - xm3) / xr3;

  float o0 = b2[0], o1 = b2[1], o2 = b2[2], o3 = b2[3];
#pragma unroll 8
  for (int j = 0; j < HID; ++j) {
    float h = b1[j];
    h = fmaf(xn0, W1[0 * HID + j], h);
    h = fmaf(xn1, W1[1 * HID + j], h);
    h = fmaf(xn2, W1[2 * HID + j], h);
    h = fmaf(xn3, W1[3 * HID + j], h);
    h = fmaxf(h, 0.0f);
    o0 = fmaf(h, W2[j * 4 + 0], o0);
    o1 = fmaf(h, W2[j * 4 + 1], o1);
    o2 = fmaf(h, W2[j * 4 + 2], o2);
    o3 = fmaf(h, W2[j * 4 + 3], o3);
  }

  const float ym0 = Y_min[0], ym1 = Y_min[1], ym2 = Y_min[2], ym3 = Y_min[3];
  const float e0 = (1.0f / (1.0f + expf(-o0))) * (Y_max[0] - ym0) + ym0;
  const float e1 = (1.0f / (1.0f + expf(-o1))) * (Y_max[1] - ym1) + ym1;
  const float e2 = (1.0f / (1.0f + expf(-o2))) * (Y_max[2] - ym2) + ym2;
  const float e3 = (1.0f / (1.0f + expf(-o3))) * (Y_max[3] - ym3) + ym3;
  const float slope = (e1 - e0) / (e3 - e2);

  float* row = eta_ws + n * ETA_STRIDE;
  row[0] = e0; row[1] = e1; row[2] = e2; row[3] = e3; row[4] = slope;
  row[5] = 0.0f; row[6] = 0.0f; row[7] = 0.0f;
}

// ---------------------------------------------------------------------------
// Kernel 2: streaming piecewise-linear map, float4 grid-stride.
// out = z < e2 ? e0 : (z <= e3 ? e0 + slope*(z - e2) : e1)
// eta table (4 KiB) staged in LDS once per block; reads are wave-uniform
// (n = i4 >> 17) so they broadcast conflict-free.
// ---------------------------------------------------------------------------
__global__ __launch_bounds__(256) void hs_kernel(
    const float* __restrict__ z, const float* __restrict__ eta_ws,
    float* __restrict__ out, int total4) {
  __shared__ float s_eta[N_ROWS * ETA_STRIDE];

  // stage eta table: 1024 floats = 256 threads x 1 float4
  {
    const float4* src = reinterpret_cast<const float4*>(eta_ws);
    float4* dst = reinterpret_cast<float4*>(s_eta);
    dst[threadIdx.x] = src[threadIdx.x];
  }
  __syncthreads();

  const float4* __restrict__ z4 = reinterpret_cast<const float4*>(z);
  float4* __restrict__ o4 = reinterpret_cast<float4*>(out);

  const int stride = gridDim.x * 256;
  for (int i = blockIdx.x * 256 + threadIdx.x; i < total4; i += stride) {
    const int n = i >> 17;  // HW4 = 2^17 float4 per row
    const float* row = &s_eta[n * ETA_STRIDE];
    const float e0 = row[0], e1 = row[1], e2 = row[2], e3 = row[3], sl = row[4];

    const float4 zv = z4[i];
    float4 r;
    r.x = (zv.x < e2) ? e0 : ((zv.x <= e3) ? fmaf(sl, zv.x - e2, e0) : e1);
    r.y = (zv.y < e2) ? e0 : ((zv.y <= e3) ? fmaf(sl, zv.y - e2, e0) : e1);
    r.z = (zv.z < e2) ? e0 : ((zv.z <= e3) ? fmaf(sl, zv.z - e2, e0) : e1);
    r.w = (zv.w < e2) ? e0 : ((zv.w <= e3) ? fmaf(sl, zv.w - e2, e0) : e1);
    o4[i] = r;
  }
}

extern "C" void kernel_launch(void* const* d_in, const int* in_sizes, int n_in,
                              void* d_out, int out_size, void* d_ws, size_t ws_size,
                              hipStream_t stream) {
  const float* z     = (const float*)d_in[0];
  const float* rt_   = (const float*)d_in[1];
  const float* noise = (const float*)d_in[2];
  const float* X_min = (const float*)d_in[3];
  const float* X_max = (const float*)d_in[4];
  const float* Y_min = (const float*)d_in[5];
  const float* Y_max = (const float*)d_in[6];
  const float* W1    = (const float*)d_in[7];
  const float* b1    = (const float*)d_in[8];
  const float* W2    = (const float*)d_in[9];
  const float* b2    = (const float*)d_in[10];
  float* out = (float*)d_out;
  float* eta_ws = (float*)d_ws;  // 128*8 floats = 4 KiB

  eta_kernel<<<1, N_ROWS, 0, stream>>>(rt_, noise, X_min, X_max, Y_min, Y_max,
                                       W1, b1, W2, b2, eta_ws);

  const int total4 = out_size / 4;  // 16777216
  const int blocks = 2048;          // ~8 blocks/CU, grid-stride
  hs_kernel<<<blocks, 256, 0, stream>>>(z, eta_ws, out, total4);
}